// Round 3
// baseline (296.127 us; speedup 1.0000x reference)
//
#include <hip/hip_runtime.h>

#define NQ 8
#define BINS 256
#define D 128
#define RPB 16            // rows per block
#define THREADS 256
#define RGN 8             // row groups (t & 7), 2 rows each
#define BGN 32            // bin groups (t >> 3), 8 bins each
#define RSTRIDE 132       // 128 + 4 pad

__global__ __launch_bounds__(THREADS) void rvq_kernel(
    const float* __restrict__ hidden,     // [N, D]
    const float* __restrict__ codebooks,  // [NQ, BINS, D]
    float* __restrict__ out_codes,        // [NQ, N] stored as float
    float* __restrict__ out_quant,        // [N, D]
    int N)
{
    __shared__ float res[RPB * RSTRIDE];
    __shared__ float c2s[BINS];                 // ||c||^2 per bin, this level
    __shared__ float red_dist[RPB][BGN];
    __shared__ int   red_idx[RPB][BGN];
    __shared__ int   win[RPB];

    const int t = threadIdx.x;
    const int row0 = blockIdx.x * RPB;

    // ---- load hidden rows into LDS residual (coalesced float4) ----
    #pragma unroll
    for (int i = 0; i < 2; ++i) {
        int f4 = t + i * THREADS;
        int r  = f4 >> 5;
        int c4 = f4 & 31;
        float4 v = ((const float4*)hidden)[(size_t)(row0 + r) * 32 + c4];
        float* dst = &res[r * RSTRIDE + (c4 << 2)];
        dst[0] = v.x; dst[1] = v.y; dst[2] = v.z; dst[3] = v.w;
    }
    __syncthreads();

    const int rg = t & (RGN - 1);      // row group: rows {2rg, 2rg+1}
    const int bg = t >> 3;             // bin group: bins {8bg .. 8bg+7}
    const int r0 = rg * 2;

    for (int level = 0; level < NQ; ++level) {
        const float*  cb  = codebooks + level * BINS * D;
        const float4* cb4 = (const float4*)cb;

        // ---- cooperative ||c||^2: coalesced loads + 32-lane shuffle reduce ----
        #pragma unroll 4
        for (int rr = 0; rr < 32; ++rr) {
            int idx = rr * THREADS + t;        // f4 index: bin = idx>>5, kc = idx&31
            float4 v = cb4[idx];
            float p = fmaf(v.x, v.x, fmaf(v.y, v.y, fmaf(v.z, v.z, v.w * v.w)));
            p += __shfl_xor(p, 16, 64);
            p += __shfl_xor(p, 8, 64);
            p += __shfl_xor(p, 4, 64);
            p += __shfl_xor(p, 2, 64);
            p += __shfl_xor(p, 1, 64);
            if ((t & 31) == 0) c2s[idx >> 5] = p;
        }
        __syncthreads();

        const float4* cbb = (const float4*)(cb + (bg * 8) * D);

        float4 acc0[8], acc1[8];
        #pragma unroll
        for (int j = 0; j < 8; ++j) {
            acc0[j] = make_float4(0.f, 0.f, 0.f, 0.f);
            acc1[j] = make_float4(0.f, 0.f, 0.f, 0.f);
        }

        const float4* ra_base = (const float4*)&res[(r0    ) * RSTRIDE];
        const float4* rb_base = (const float4*)&res[(r0 + 1) * RSTRIDE];

        #pragma unroll 2
        for (int kc = 0; kc < 32; ++kc) {
            float4 ra = ra_base[kc];
            float4 rb = rb_base[kc];
            #pragma unroll
            for (int j = 0; j < 8; ++j) {
                float4 c = cbb[j * 32 + kc];
                acc0[j].x = fmaf(ra.x, c.x, acc0[j].x);
                acc0[j].y = fmaf(ra.y, c.y, acc0[j].y);
                acc0[j].z = fmaf(ra.z, c.z, acc0[j].z);
                acc0[j].w = fmaf(ra.w, c.w, acc0[j].w);
                acc1[j].x = fmaf(rb.x, c.x, acc1[j].x);
                acc1[j].y = fmaf(rb.y, c.y, acc1[j].y);
                acc1[j].z = fmaf(rb.z, c.z, acc1[j].z);
                acc1[j].w = fmaf(rb.w, c.w, acc1[j].w);
            }
        }

        // per-thread best over its 8 bins (key = ||c||^2 - 2 r.c), strict <
        {
            float best0 = INFINITY, best1 = INFINITY;
            int   bi0 = 0, bi1 = 0;
            #pragma unroll
            for (int j = 0; j < 8; ++j) {
                int b = bg * 8 + j;
                float c2 = c2s[b];
                float d0 = (acc0[j].x + acc0[j].y) + (acc0[j].z + acc0[j].w);
                float d1 = (acc1[j].x + acc1[j].y) + (acc1[j].z + acc1[j].w);
                float k0 = fmaf(-2.f, d0, c2);
                float k1 = fmaf(-2.f, d1, c2);
                if (k0 < best0) { best0 = k0; bi0 = b; }
                if (k1 < best1) { best1 = k1; bi1 = b; }
            }
            red_dist[r0    ][bg] = best0;
            red_idx [r0    ][bg] = bi0;
            red_dist[r0 + 1][bg] = best1;
            red_idx [r0 + 1][bg] = bi1;
        }
        __syncthreads();

        // ---- per-row argmin reduce + code write (threads 0..15) ----
        if (t < RPB) {
            float bd = red_dist[t][0];
            int   bi = red_idx[t][0];
            #pragma unroll
            for (int j = 1; j < BGN; ++j) {
                float dj = red_dist[t][j];
                int   ij = red_idx[t][j];
                if (dj < bd || (dj == bd && ij < bi)) { bd = dj; bi = ij; }
            }
            win[t] = bi;
            out_codes[(size_t)level * N + row0 + t] = (float)bi;
        }
        __syncthreads();

        // ---- residual update: row = t>>4, 8 floats per thread ----
        {
            int r = t >> 4;
            int g8 = t & 15;
            int w = win[r];
            const float* c = cb + w * D + g8 * 8;
            float* rp = &res[r * RSTRIDE + g8 * 8];
            #pragma unroll
            for (int k = 0; k < 8; ++k) rp[k] -= c[k];
        }
        __syncthreads();
    }

    // ---- epilogue: quantized = hidden - residual ----
    #pragma unroll
    for (int i = 0; i < 2; ++i) {
        int f4 = t + i * THREADS;
        int r  = f4 >> 5;
        int c4 = f4 & 31;
        float4 h = ((const float4*)hidden)[(size_t)(row0 + r) * 32 + c4];
        const float* rs = &res[r * RSTRIDE + (c4 << 2)];
        float4 q;
        q.x = h.x - rs[0]; q.y = h.y - rs[1]; q.z = h.z - rs[2]; q.w = h.w - rs[3];
        ((float4*)out_quant)[(size_t)(row0 + r) * 32 + c4] = q;
    }
}

extern "C" void kernel_launch(void* const* d_in, const int* in_sizes, int n_in,
                              void* d_out, int out_size, void* d_ws, size_t ws_size,
                              hipStream_t stream) {
    const float* hidden    = (const float*)d_in[0];
    const float* codebooks = (const float*)d_in[1];
    float* out = (float*)d_out;
    const int N = in_sizes[0] / D;                 // 8192
    float* out_codes = out;                        // [NQ, N]
    float* out_quant = out + (size_t)NQ * N;       // [N, D]
    dim3 grid(N / RPB);
    rvq_kernel<<<grid, THREADS, 0, stream>>>(hidden, codebooks, out_codes, out_quant, N);
}

// Round 6
// 131.251 us; speedup vs baseline: 2.2562x; 2.2562x over previous
//
#include <hip/hip_runtime.h>

#define NQ 8
#define BINS 256
#define D 128
#define RPB 32            // rows per block
#define THREADS 512
#define RSTRIDE 132       // res fp32 row stride (pad)

typedef short s8v __attribute__((ext_vector_type(8)));   // 8 bf16 in 4 VGPRs
typedef float f4v __attribute__((ext_vector_type(4)));   // MFMA accumulator

static __device__ __forceinline__ unsigned short bf16_rtne(float x) {
    unsigned u = __float_as_uint(x);
    unsigned r = (u + 0x7fffu + ((u >> 16) & 1u)) >> 16;
    return (unsigned short)r;
}
static __device__ __forceinline__ float bf16_to_f(unsigned short h) {
    return __uint_as_float(((unsigned)h) << 16);
}
struct Split3 { short h, m, l; };
static __device__ __forceinline__ Split3 split3(float x) {
    Split3 s;
    unsigned short hb = bf16_rtne(x);
    float r1 = x - bf16_to_f(hb);
    unsigned short mb = bf16_rtne(r1);
    unsigned short lb = bf16_rtne(r1 - bf16_to_f(mb));
    s.h = (short)hb; s.m = (short)mb; s.l = (short)lb;
    return s;
}
static __device__ __forceinline__ unsigned long long shfl_xor_u64(unsigned long long v, int mask) {
    int lo = (int)(unsigned)(v & 0xffffffffull);
    int hi = (int)(unsigned)(v >> 32);
    lo = __shfl_xor(lo, mask, 64);
    hi = __shfl_xor(hi, mask, 64);
    return ((unsigned long long)(unsigned)hi << 32) | (unsigned)lo;
}
static __device__ __forceinline__ unsigned long long u64min(unsigned long long a, unsigned long long b) {
    return a < b ? a : b;
}

// ---- prep: codebooks fp32 -> bf16 3-way split (swizzled [L][kchunk][bin][8]) + ||c||^2 ----
__global__ __launch_bounds__(256) void rvq_prep(
    const float* __restrict__ cb, short* __restrict__ cb_hi,
    short* __restrict__ cb_mid, short* __restrict__ cb_lo,
    float* __restrict__ c2)
{
    __shared__ float st[64 * RSTRIDE];
    const int L = blockIdx.x >> 2;     // level
    const int o = blockIdx.x & 3;      // bin-quarter (64 bins)
    const int t = threadIdx.x;

    // stage 64 bins (32 KB) coalesced
    const float4* src = (const float4*)(cb + ((size_t)L * BINS + o * 64) * D);
    #pragma unroll
    for (int i = 0; i < 8; ++i) {
        int f4 = i * 256 + t;              // 2048 f4
        int row = f4 >> 5, c4 = f4 & 31;
        float4 v = src[f4];
        float* d = &st[row * RSTRIDE + c4 * 4];
        d[0] = v.x; d[1] = v.y; d[2] = v.z; d[3] = v.w;
    }
    __syncthreads();

    // convert: 1024 tasks (bin 0..63 x kc 0..15), 4 per thread
    float csum[4];
    #pragma unroll
    for (int i = 0; i < 4; ++i) {
        int bin = i * 16 + (t >> 4);
        int kc  = t & 15;
        const float* p = &st[bin * RSTRIDE + kc * 8];
        s8v h8, m8, l8;
        float s = 0.f;
        #pragma unroll
        for (int j = 0; j < 8; ++j) {
            float x = p[j];
            Split3 sp = split3(x);
            h8[j] = sp.h; m8[j] = sp.m; l8[j] = sp.l;
            s = fmaf(x, x, s);
        }
        int idx = (L * 16 + kc) * BINS + (o * 64 + bin);
        ((s8v*)cb_hi)[idx]  = h8;
        ((s8v*)cb_mid)[idx] = m8;
        ((s8v*)cb_lo)[idx]  = l8;
        csum[i] = s;
    }
    // ||c||^2: 16-lane tree over kc chunks (pairwise-class accuracy)
    #pragma unroll
    for (int i = 0; i < 4; ++i) {
        float s = csum[i];
        s += __shfl_xor(s, 1, 64);
        s += __shfl_xor(s, 2, 64);
        s += __shfl_xor(s, 4, 64);
        s += __shfl_xor(s, 8, 64);
        if ((t & 15) == 0)
            c2[L * BINS + o * 64 + i * 16 + (t >> 4)] = s;
    }
}

// ---- main: per-block 32 rows, all 8 levels; distances via 3-way-split MFMA ----
__global__ __launch_bounds__(THREADS) void rvq_kernel(
    const float* __restrict__ hidden,     // [N, D]
    const float* __restrict__ cb_f32,     // [NQ, BINS, D]
    const short* __restrict__ cb_hi,      // swizzled bf16 splits
    const short* __restrict__ cb_mid,
    const short* __restrict__ cb_lo,
    const float* __restrict__ c2p,        // [NQ, BINS]
    float* __restrict__ out_codes,        // [NQ, N] as float
    float* __restrict__ out_quant,        // [N, D]
    int N)
{
    __shared__ float res[RPB * RSTRIDE];          // 16.9 KB
    __shared__ short ah[2 * 4 * 512];             // A hi frags  [mt][ks][512]
    __shared__ short am[2 * 4 * 512];
    __shared__ short al[2 * 4 * 512];
    __shared__ unsigned long long redw[RPB][8];
    __shared__ int win[RPB];

    const int t = threadIdx.x;
    const int w = t >> 6;                 // wave 0..7
    const int l = t & 63;
    const int quad = l >> 4;
    const int m = l & 15;
    const int row0 = blockIdx.x * RPB;
    const int woff = w * 32;              // this wave's bin offset (32 bins)

    // stage hidden rows -> fp32 residual in LDS
    #pragma unroll
    for (int i = 0; i < 2; ++i) {
        int f4 = i * THREADS + t;
        int r  = f4 >> 5;
        int c4 = f4 & 31;
        float4 v = ((const float4*)hidden)[(size_t)(row0 + r) * 32 + c4];
        float* dst = &res[r * RSTRIDE + (c4 << 2)];
        dst[0] = v.x; dst[1] = v.y; dst[2] = v.z; dst[3] = v.w;
    }
    __syncthreads();

    const s8v* bhp = (const s8v*)cb_hi;
    const s8v* bmp = (const s8v*)cb_mid;
    const s8v* blp = (const s8v*)cb_lo;

    for (int level = 0; level < NQ; ++level) {
        // ---- convert residual -> 3-way split A-fragments (fragment-order LDS) ----
        {
            int r  = t >> 4;              // row 0..31
            int g8 = t & 15;              // k-chunk 0..15
            int mt = r >> 4, rr = r & 15;
            const float* rp = &res[r * RSTRIDE + g8 * 8];
            float4 v0 = *(const float4*)rp;
            float4 v1 = *(const float4*)(rp + 4);
            float xs[8] = {v0.x, v0.y, v0.z, v0.w, v1.x, v1.y, v1.z, v1.w};
            s8v h8, m8, l8;
            #pragma unroll
            for (int j = 0; j < 8; ++j) {
                Split3 sp = split3(xs[j]);
                h8[j] = sp.h; m8[j] = sp.m; l8[j] = sp.l;
            }
            int base = ((mt * 4 + (g8 >> 2)) * 512) + (((g8 & 3) * 16 + rr) * 8);
            *(s8v*)&ah[base] = h8;
            *(s8v*)&am[base] = m8;
            *(s8v*)&al[base] = l8;
        }
        __syncthreads();

        // ---- A fragments: lane-contiguous, conflict-free ----
        s8v afh[2][4], afm[2][4], afl[2][4];
        #pragma unroll
        for (int mt = 0; mt < 2; ++mt)
            #pragma unroll
            for (int ks = 0; ks < 4; ++ks) {
                int off = (mt * 4 + ks) * 512 + l * 8;
                afh[mt][ks] = *(const s8v*)&ah[off];
                afm[mt][ks] = *(const s8v*)&am[off];
                afl[mt][ks] = *(const s8v*)&al[off];
            }

        unsigned long long best[2][4];
        #pragma unroll
        for (int mt = 0; mt < 2; ++mt)
            #pragma unroll
            for (int i = 0; i < 4; ++i) best[mt][i] = ~0ull;

        #pragma unroll
        for (int nt = 0; nt < 2; ++nt) {
            const int bin = woff + nt * 16 + m;
            s8v bh[4], bm[4], bl[4];
            #pragma unroll
            for (int ks = 0; ks < 4; ++ks) {
                int idx = (level * 16 + ks * 4 + quad) * BINS + bin;
                bh[ks] = bhp[idx];
                bm[ks] = bmp[idx];
                bl[ks] = blp[idx];
            }
            float c2v = c2p[level * BINS + bin];
            #pragma unroll
            for (int mt = 0; mt < 2; ++mt) {
                f4v a0 = {0.f, 0.f, 0.f, 0.f};   // hh
                f4v a1 = {0.f, 0.f, 0.f, 0.f};   // hm + mh   (~2^-9 scale)
                f4v a2 = {0.f, 0.f, 0.f, 0.f};   // mm+hl+lh  (~2^-18 scale)
                #pragma unroll
                for (int ks = 0; ks < 4; ++ks) {
                    a0 = __builtin_amdgcn_mfma_f32_16x16x32_bf16(afh[mt][ks], bh[ks], a0, 0, 0, 0);
                    a1 = __builtin_amdgcn_mfma_f32_16x16x32_bf16(afh[mt][ks], bm[ks], a1, 0, 0, 0);
                    a1 = __builtin_amdgcn_mfma_f32_16x16x32_bf16(afm[mt][ks], bh[ks], a1, 0, 0, 0);
                    a2 = __builtin_amdgcn_mfma_f32_16x16x32_bf16(afm[mt][ks], bm[ks], a2, 0, 0, 0);
                    a2 = __builtin_amdgcn_mfma_f32_16x16x32_bf16(afh[mt][ks], bl[ks], a2, 0, 0, 0);
                    a2 = __builtin_amdgcn_mfma_f32_16x16x32_bf16(afl[mt][ks], bh[ks], a2, 0, 0, 0);
                }
                #pragma unroll
                for (int i = 0; i < 4; ++i) {
                    float dot = a0[i] + (a1[i] + a2[i]);      // small terms first
                    float k = fmaf(-2.f, dot, c2v);
                    unsigned u = __float_as_uint(k);
                    u = (u & 0x80000000u) ? ~u : (u | 0x80000000u);
                    unsigned long long key = ((unsigned long long)u << 32) | (unsigned)bin;
                    best[mt][i] = u64min(best[mt][i], key);
                }
            }
        }

        // ---- cross-lane argmin within 16-lane groups ----
        #pragma unroll
        for (int mt = 0; mt < 2; ++mt)
            #pragma unroll
            for (int i = 0; i < 4; ++i) {
                unsigned long long p = best[mt][i];
                p = u64min(p, shfl_xor_u64(p, 1));
                p = u64min(p, shfl_xor_u64(p, 2));
                p = u64min(p, shfl_xor_u64(p, 4));
                p = u64min(p, shfl_xor_u64(p, 8));
                if (m == 0) redw[mt * 16 + quad * 4 + i][w] = p;
            }
        __syncthreads();

        // ---- cross-wave reduce, code write ----
        if (t < RPB) {
            unsigned long long mn = redw[t][0];
            #pragma unroll
            for (int j = 1; j < 8; ++j) mn = u64min(mn, redw[t][j]);
            int bi = (int)(mn & 0xffffffffull);
            win[t] = bi;
            out_codes[(size_t)level * N + row0 + t] = (float)bi;
        }
        __syncthreads();

        // ---- fp32 residual update (elementwise, matches reference exactly) ----
        {
            int r  = t >> 4;
            int g8 = t & 15;
            int wb = win[r];
            const float4* cp = (const float4*)(cb_f32 + ((size_t)level * BINS + wb) * D + g8 * 8);
            float4 c0 = cp[0];
            float4 c1 = cp[1];
            float* rp = &res[r * RSTRIDE + g8 * 8];
            rp[0] -= c0.x; rp[1] -= c0.y; rp[2] -= c0.z; rp[3] -= c0.w;
            rp[4] -= c1.x; rp[5] -= c1.y; rp[6] -= c1.z; rp[7] -= c1.w;
        }
        __syncthreads();
    }

    // ---- epilogue: quantized = hidden - residual ----
    #pragma unroll
    for (int i = 0; i < 2; ++i) {
        int f4 = i * THREADS + t;
        int r  = f4 >> 5;
        int c4 = f4 & 31;
        float4 h = ((const float4*)hidden)[(size_t)(row0 + r) * 32 + c4];
        const float* rs = &res[r * RSTRIDE + (c4 << 2)];
        float4 q;
        q.x = h.x - rs[0]; q.y = h.y - rs[1]; q.z = h.z - rs[2]; q.w = h.w - rs[3];
        ((float4*)out_quant)[(size_t)(row0 + r) * 32 + c4] = q;
    }
}

extern "C" void kernel_launch(void* const* d_in, const int* in_sizes, int n_in,
                              void* d_out, int out_size, void* d_ws, size_t ws_size,
                              hipStream_t stream) {
    const float* hidden    = (const float*)d_in[0];
    const float* codebooks = (const float*)d_in[1];
    float* out = (float*)d_out;
    const int N = in_sizes[0] / D;                 // 8192
    float* out_codes = out;                        // [NQ, N]
    float* out_quant = out + (size_t)NQ * N;       // [N, D]

    char* ws = (char*)d_ws;
    short* cb_hi  = (short*)ws;                    // 512 KB
    short* cb_mid = (short*)(ws +  512 * 1024);    // 512 KB
    short* cb_lo  = (short*)(ws + 1024 * 1024);    // 512 KB
    float* c2     = (float*)(ws + 1536 * 1024);    // 8 KB

    rvq_prep<<<dim3(NQ * 4), 256, 0, stream>>>(codebooks, cb_hi, cb_mid, cb_lo, c2);
    rvq_kernel<<<dim3(N / RPB), THREADS, 0, stream>>>(
        hidden, codebooks, cb_hi, cb_mid, cb_lo, c2, out_codes, out_quant, N);
}

// Round 7
// 110.910 us; speedup vs baseline: 2.6700x; 1.1834x over previous
//
#include <hip/hip_runtime.h>

#define NQ 8
#define BINS 256
#define D 128
#define RPB 32            // rows per block
#define THREADS 512
#define RSTRIDE 132       // prep staging stride
#define FREG 520          // shorts per frag region (512 + 8 pad -> bank decorrelation)

typedef short s8v __attribute__((ext_vector_type(8)));   // 8 bf16 in 4 VGPRs
typedef float f4v __attribute__((ext_vector_type(4)));   // MFMA accumulator

static __device__ __forceinline__ unsigned short bf16_rtne(float x) {
    unsigned u = __float_as_uint(x);
    unsigned r = (u + 0x7fffu + ((u >> 16) & 1u)) >> 16;
    return (unsigned short)r;
}
static __device__ __forceinline__ float bf16_to_f(unsigned short h) {
    return __uint_as_float(((unsigned)h) << 16);
}
struct Split3 { short h, m, l; };
static __device__ __forceinline__ Split3 split3(float x) {
    Split3 s;
    unsigned short hb = bf16_rtne(x);
    float r1 = x - bf16_to_f(hb);
    unsigned short mb = bf16_rtne(r1);
    unsigned short lb = bf16_rtne(r1 - bf16_to_f(mb));
    s.h = (short)hb; s.m = (short)mb; s.l = (short)lb;
    return s;
}
static __device__ __forceinline__ unsigned long long shfl_xor_u64(unsigned long long v, int mask) {
    int lo = (int)(unsigned)(v & 0xffffffffull);
    int hi = (int)(unsigned)(v >> 32);
    lo = __shfl_xor(lo, mask, 64);
    hi = __shfl_xor(hi, mask, 64);
    return ((unsigned long long)(unsigned)hi << 32) | (unsigned)lo;
}
static __device__ __forceinline__ unsigned long long u64min(unsigned long long a, unsigned long long b) {
    return a < b ? a : b;
}

// ---- prep: codebooks fp32 -> bf16 3-way split (swizzled [L][kchunk][bin][8]) + ||c||^2 ----
// 128 blocks: (level, 16-bin group)
__global__ __launch_bounds__(256) void rvq_prep(
    const float* __restrict__ cb, short* __restrict__ cb_hi,
    short* __restrict__ cb_mid, short* __restrict__ cb_lo,
    float* __restrict__ c2)
{
    __shared__ float st[16 * RSTRIDE];
    const int L = blockIdx.x >> 4;     // level
    const int o = blockIdx.x & 15;     // 16-bin group
    const int t = threadIdx.x;

    const float4* src = (const float4*)(cb + ((size_t)L * BINS + o * 16) * D);
    #pragma unroll
    for (int i = 0; i < 2; ++i) {
        int f4 = i * 256 + t;              // 512 f4 total
        int row = f4 >> 5, c4 = f4 & 31;
        float4 v = src[f4];
        float* d = &st[row * RSTRIDE + c4 * 4];
        d[0] = v.x; d[1] = v.y; d[2] = v.z; d[3] = v.w;
    }
    __syncthreads();

    const int bin = t >> 4;            // 0..15
    const int kc  = t & 15;            // 0..15
    const float* p = &st[bin * RSTRIDE + kc * 8];
    s8v h8, m8, l8;
    float s = 0.f;
    #pragma unroll
    for (int j = 0; j < 8; ++j) {
        float x = p[j];
        Split3 sp = split3(x);
        h8[j] = sp.h; m8[j] = sp.m; l8[j] = sp.l;
        s = fmaf(x, x, s);
    }
    int idx = (L * 16 + kc) * BINS + (o * 16 + bin);
    ((s8v*)cb_hi)[idx]  = h8;
    ((s8v*)cb_mid)[idx] = m8;
    ((s8v*)cb_lo)[idx]  = l8;
    // ||c||^2: tree over kc within 16-lane groups (same order as R6 - passed)
    s += __shfl_xor(s, 1, 64);
    s += __shfl_xor(s, 2, 64);
    s += __shfl_xor(s, 4, 64);
    s += __shfl_xor(s, 8, 64);
    if (kc == 0) c2[L * BINS + o * 16 + bin] = s;
}

// frag store: thread owns (row rr_, kchunk g8); bank-balanced swizzle
static __device__ __forceinline__ void frag_store(
    const float* rres, short* ah, short* am, short* al, int rr_, int g8)
{
    s8v h8, m8, l8;
    #pragma unroll
    for (int j = 0; j < 8; ++j) {
        Split3 sp = split3(rres[j]);
        h8[j] = sp.h; m8[j] = sp.m; l8[j] = sp.l;
    }
    int q = g8 & 3;
    int reg = (rr_ >> 4) * 4 + (g8 >> 2);          // mt*4 + ks
    int idx16 = q * 16 + (((rr_ & 15) + 4 * q) & 15);
    int off = reg * FREG + idx16 * 8;
    *(s8v*)&ah[off] = h8;
    *(s8v*)&am[off] = m8;
    *(s8v*)&al[off] = l8;
}

// ---- main: per-block 32 rows, all 8 levels; residual in registers ----
__global__ __launch_bounds__(THREADS, 2) void rvq_kernel(
    const float* __restrict__ hidden,     // [N, D]
    const float* __restrict__ cb_f32,     // [NQ, BINS, D]
    const short* __restrict__ cb_hi,      // swizzled bf16 splits
    const short* __restrict__ cb_mid,
    const short* __restrict__ cb_lo,
    const float* __restrict__ c2p,        // [NQ, BINS]
    float* __restrict__ out_codes,        // [NQ, N] as float
    float* __restrict__ out_quant,        // [N, D]
    int N)
{
    __shared__ short ah[8 * FREG];        // 8 regions (mt*4+ks)
    __shared__ short am[8 * FREG];
    __shared__ short al[8 * FREG];
    __shared__ unsigned long long redw[RPB][8];

    const int t = threadIdx.x;
    const int w = t >> 6;                 // wave 0..7
    const int l = t & 63;
    const int quad = l >> 4;
    const int m = l & 15;
    const int row0 = blockIdx.x * RPB;
    const int woff = w * 32;              // this wave's 32-bin window
    const int rr_ = t >> 4;               // owned row 0..31
    const int g8 = t & 15;                // owned k-chunk 0..15

    // residual lives in registers: thread owns row rr_, dims [g8*8, g8*8+8)
    float rres[8];
    {
        const float4* hp = (const float4*)(hidden + (size_t)(row0 + rr_) * D + g8 * 8);
        float4 v0 = hp[0], v1 = hp[1];
        rres[0] = v0.x; rres[1] = v0.y; rres[2] = v0.z; rres[3] = v0.w;
        rres[4] = v1.x; rres[5] = v1.y; rres[6] = v1.z; rres[7] = v1.w;
    }
    frag_store(rres, ah, am, al, rr_, g8);

    const s8v* bhp = (const s8v*)cb_hi;
    const s8v* bmp = (const s8v*)cb_mid;
    const s8v* blp = (const s8v*)cb_lo;

    for (int level = 0; level < NQ; ++level) {
        // ---- B prefetch: level-only dependent, issued before the barrier ----
        s8v bh[2][4], bm[2][4], bl[2][4];
        float c2v[2];
        #pragma unroll
        for (int nt = 0; nt < 2; ++nt) {
            int bin = woff + nt * 16 + m;
            c2v[nt] = c2p[level * BINS + bin];
            #pragma unroll
            for (int ks = 0; ks < 4; ++ks) {
                int idx = (level * 16 + ks * 4 + quad) * BINS + bin;
                bh[nt][ks] = bhp[idx];
                bm[nt][ks] = bmp[idx];
                bl[nt][ks] = blp[idx];
            }
        }
        __syncthreads();   // frag writes (prev iter / bootstrap) visible

        // ---- A fragments (swizzled read, conflict-free) ----
        s8v afh[2][4], afm[2][4], afl[2][4];
        #pragma unroll
        for (int mt = 0; mt < 2; ++mt)
            #pragma unroll
            for (int ks = 0; ks < 4; ++ks) {
                int idx16 = quad * 16 + ((m + 4 * quad) & 15);
                int off = (mt * 4 + ks) * FREG + idx16 * 8;
                afh[mt][ks] = *(const s8v*)&ah[off];
                afm[mt][ks] = *(const s8v*)&am[off];
                afl[mt][ks] = *(const s8v*)&al[off];
            }

        unsigned long long best[2][4];
        #pragma unroll
        for (int mt = 0; mt < 2; ++mt)
            #pragma unroll
            for (int i = 0; i < 4; ++i) best[mt][i] = ~0ull;

        #pragma unroll
        for (int nt = 0; nt < 2; ++nt) {
            const int bin = woff + nt * 16 + m;
            #pragma unroll
            for (int mt = 0; mt < 2; ++mt) {
                f4v a0 = {0.f, 0.f, 0.f, 0.f};   // hh
                f4v a1 = {0.f, 0.f, 0.f, 0.f};   // hm + mh
                f4v a2 = {0.f, 0.f, 0.f, 0.f};   // mm + hl + lh
                #pragma unroll
                for (int ks = 0; ks < 4; ++ks) {
                    a0 = __builtin_amdgcn_mfma_f32_16x16x32_bf16(afh[mt][ks], bh[nt][ks], a0, 0, 0, 0);
                    a1 = __builtin_amdgcn_mfma_f32_16x16x32_bf16(afh[mt][ks], bm[nt][ks], a1, 0, 0, 0);
                    a1 = __builtin_amdgcn_mfma_f32_16x16x32_bf16(afm[mt][ks], bh[nt][ks], a1, 0, 0, 0);
                    a2 = __builtin_amdgcn_mfma_f32_16x16x32_bf16(afm[mt][ks], bm[nt][ks], a2, 0, 0, 0);
                    a2 = __builtin_amdgcn_mfma_f32_16x16x32_bf16(afh[mt][ks], bl[nt][ks], a2, 0, 0, 0);
                    a2 = __builtin_amdgcn_mfma_f32_16x16x32_bf16(afl[mt][ks], bh[nt][ks], a2, 0, 0, 0);
                }
                #pragma unroll
                for (int i = 0; i < 4; ++i) {
                    float dot = a0[i] + (a1[i] + a2[i]);      // small terms first
                    float k = fmaf(-2.f, dot, c2v[nt]);
                    unsigned u = __float_as_uint(k);
                    u = (u & 0x80000000u) ? ~u : (u | 0x80000000u);
                    unsigned long long key = ((unsigned long long)u << 32) | (unsigned)bin;
                    best[mt][i] = u64min(best[mt][i], key);
                }
            }
        }

        // ---- argmin within 16-lane groups; stash per-wave result ----
        #pragma unroll
        for (int mt = 0; mt < 2; ++mt)
            #pragma unroll
            for (int i = 0; i < 4; ++i) {
                unsigned long long p = best[mt][i];
                p = u64min(p, shfl_xor_u64(p, 1));
                p = u64min(p, shfl_xor_u64(p, 2));
                p = u64min(p, shfl_xor_u64(p, 4));
                p = u64min(p, shfl_xor_u64(p, 8));
                if (m == 0) redw[mt * 16 + quad * 4 + i][w] = p;
            }
        __syncthreads();

        // ---- every thread reduces its own row's 8 wave-results (broadcast reads) ----
        unsigned long long mn = redw[rr_][0];
        #pragma unroll
        for (int j = 1; j < 8; ++j) mn = u64min(mn, redw[rr_][j]);
        const int wb = (int)(mn & 0xffffffffull);
        if (g8 == 0)
            out_codes[(size_t)level * N + row0 + rr_] = (float)wb;

        // ---- fp32 residual update in registers (same arithmetic as reference) ----
        {
            const float4* cp = (const float4*)(cb_f32 + ((size_t)level * BINS + wb) * D + g8 * 8);
            float4 c0 = cp[0], c1 = cp[1];
            rres[0] -= c0.x; rres[1] -= c0.y; rres[2] -= c0.z; rres[3] -= c0.w;
            rres[4] -= c1.x; rres[5] -= c1.y; rres[6] -= c1.z; rres[7] -= c1.w;
        }
        frag_store(rres, ah, am, al, rr_, g8);   // next level's A (unused at level 7, harmless)
    }

    // ---- epilogue: quantized = hidden - residual (registers) ----
    {
        const float4* hp = (const float4*)(hidden + (size_t)(row0 + rr_) * D + g8 * 8);
        float4 v0 = hp[0], v1 = hp[1];
        float4 q0, q1;
        q0.x = v0.x - rres[0]; q0.y = v0.y - rres[1]; q0.z = v0.z - rres[2]; q0.w = v0.w - rres[3];
        q1.x = v1.x - rres[4]; q1.y = v1.y - rres[5]; q1.z = v1.z - rres[6]; q1.w = v1.w - rres[7];
        float4* op = (float4*)(out_quant + (size_t)(row0 + rr_) * D + g8 * 8);
        op[0] = q0; op[1] = q1;
    }
}

extern "C" void kernel_launch(void* const* d_in, const int* in_sizes, int n_in,
                              void* d_out, int out_size, void* d_ws, size_t ws_size,
                              hipStream_t stream) {
    const float* hidden    = (const float*)d_in[0];
    const float* codebooks = (const float*)d_in[1];
    float* out = (float*)d_out;
    const int N = in_sizes[0] / D;                 // 8192
    float* out_codes = out;                        // [NQ, N]
    float* out_quant = out + (size_t)NQ * N;       // [N, D]

    char* ws = (char*)d_ws;
    short* cb_hi  = (short*)ws;                    // 512 KB
    short* cb_mid = (short*)(ws +  512 * 1024);    // 512 KB
    short* cb_lo  = (short*)(ws + 1024 * 1024);    // 512 KB
    float* c2     = (float*)(ws + 1536 * 1024);    // 8 KB

    rvq_prep<<<dim3(NQ * 16), 256, 0, stream>>>(codebooks, cb_hi, cb_mid, cb_lo, c2);
    rvq_kernel<<<dim3(N / RPB), THREADS, 0, stream>>>(
        hidden, codebooks, cb_hi, cb_mid, cb_lo, c2, out_codes, out_quant, N);
}